// Round 7
// baseline (261.450 us; speedup 1.0000x reference)
//
#include <hip/hip_runtime.h>
#include <cstdint>
#include <cstddef>

// ---------------- problem constants ----------------
#define T_REAL 14884        // 4*61*61 real pixels
#define TPAD   15360        // padded to 60*256
#define CDIM   256
#define HW     3721         // 61*61
#define NRB    60           // row blocks of 256 (4 waves x 64 rows)
#define NSL    16           // column slices (grid.y)
#define TPS    15           // 64-wide j-tiles per slice (240/16)
#define NT     240          // total j-tiles
#define NPADJ  476.0f       // TPAD - T_REAL

// feats pre-scaled by sqrt(log2(e)/0.07): MFMA output IS sim*log2(e)/temp.
static constexpr float SQRT_SCALE = 4.53981598f;   // sqrt(20.6099291555566)

typedef _Float16 f16x8  __attribute__((ext_vector_type(8)));
typedef float    f32x16 __attribute__((ext_vector_type(16)));

__device__ __forceinline__ float exp2_fast(float x) {
#if __has_builtin(__builtin_amdgcn_exp2f)
    return __builtin_amdgcn_exp2f(x);
#else
    return exp2f(x);
#endif
}

// ---------------- workspace layout (bytes) ----------------
#define OFF_FEATS 0u
#define SZ_FEATS  ((unsigned)TPAD * CDIM * 2u)            // 7,864,320
#define OFF_LAB   (OFF_FEATS + SZ_FEATS)                  // TPAD ints
#define OFF_RANK  (OFF_LAB + (unsigned)TPAD * 4u)         // T_REAL ints (rounded)
#define OFF_TCL   (OFF_RANK + 59648u)                     // NT ints -> 1024
#define OFF_DONE  (OFF_TCL + 1024u)                       // 1 int (+pad to 128)
#define OFF_PART  (OFF_DONE + 128u)                       // NRB*NSL*256 float2
#define SZ_PART   ((unsigned)NRB * NSL * 256u * 8u)       // 1,966,080
#define OFF_ACC   (OFF_PART + SZ_PART)                    // 2 floats

// ---------------- k_sort: hist + scan + rank + labels + tcl + zeros ----------
// Single block, 1024 threads (16 waves). Wave-aggregated LDS cursors.
__global__ void k_sort(const int* __restrict__ targets, int* __restrict__ rank,
                       int* __restrict__ labels, int* __restrict__ tcl,
                       float* __restrict__ accum, int* __restrict__ done) {
    __shared__ int h[5], cur[5], soffs[6];
    const int tid = threadIdx.x, lane = tid & 63;
    if (tid < 5) h[tid] = 0;
    if (tid == 8) { accum[0] = 0.f; accum[1] = 0.f; }
    if (tid == 9) done[0] = 0;
    __syncthreads();

    // histogram (wave-aggregated atomics)
    for (int t = tid; t < T_REAL; t += 1024) {
        const int c = targets[t];
#pragma unroll
        for (int cl = 0; cl < 5; ++cl) {
            unsigned long long m = __ballot(c == cl);
            if (c == cl && lane == __ffsll(m) - 1) atomicAdd(&h[cl], (int)__popcll(m));
        }
    }
    __syncthreads();
    if (tid == 0) {
        int o = 0;
#pragma unroll
        for (int c = 0; c < 5; ++c) { soffs[c] = o; cur[c] = o; o += h[c]; }
        soffs[5] = o;                  // == T_REAL
    }
    __syncthreads();

    // rank + scatter sorted labels
    for (int t = tid; t < T_REAL; t += 1024) {
        const int c = targets[t];
#pragma unroll
        for (int cl = 0; cl < 5; ++cl) {
            unsigned long long m = __ballot(c == cl);
            if (c == cl) {
                const int leader = __ffsll(m) - 1;
                int base = 0;
                if (lane == leader) base = atomicAdd(&cur[cl], (int)__popcll(m));
                base = __shfl(base, leader);
                const int r = base + (int)__popcll(m & ((1ull << lane) - 1ull));
                rank[t] = r;
                labels[r] = c;
            }
        }
    }
    for (int t = T_REAL + tid; t < TPAD; t += 1024) labels[t] = -1;

    // tile classes
    for (int t = tid; t < NT; t += 1024) {
        const int lo = t * 64, hi = lo + 64;
        int tc = -2;
        if (lo >= T_REAL) tc = -1;
        else {
#pragma unroll
            for (int c = 0; c < 5; ++c)
                if (lo >= soffs[c] && hi <= soffs[c + 1]) tc = c;
        }
        tcl[t] = tc;
    }
}

// ---------------- k_prep: norm+transpose+scale+cast, scattered to sorted rows
__global__ void k_prep(const float* __restrict__ emb, const int* __restrict__ rank,
                       _Float16* __restrict__ feats) {
    const int tid = threadIdx.x;
    const int bx = blockIdx.x, n = blockIdx.y;

    if (bx == 59) {            // tail block: zero this n's share of pad rows
        const int r0 = T_REAL + n * 119;
        f16x8 z = {0, 0, 0, 0, 0, 0, 0, 0};
        for (int c = tid; c < 119 * 32; c += 256) {
            int rr = r0 + (c >> 5), cc = c & 31;
            *reinterpret_cast<f16x8*>(feats + (size_t)rr * CDIM + cc * 8) = z;
        }
        return;
    }

    __shared__ float tile[64][257];
    __shared__ float sspart[4][64];
    const int lane = tid & 63, w = tid >> 6;
    const int px0 = bx * 64;
    const int hw = px0 + lane;

    float ssq = 0.f;
    for (int ci = w; ci < CDIM; ci += 4) {
        float v = (hw < HW) ? emb[((size_t)(n * CDIM + ci)) * HW + hw] : 0.f;
        tile[lane][ci] = v;
        ssq += v * v;
    }
    sspart[w][lane] = ssq;
    __syncthreads();

    const int pp = tid >> 2, q = tid & 3;     // pixel-in-tile, channel quarter
    float s2 = sspart[q][pp];
    s2 += __shfl_xor(s2, 1);
    s2 += __shfl_xor(s2, 2);
    const float inv = SQRT_SCALE / fmaxf(sqrtf(s2), 1e-12f);

    const int hwp = px0 + pp;
    if (hwp < HW) {
        const int row = rank[n * HW + hwp];
        _Float16* dst = feats + (size_t)row * CDIM + q * 64;
#pragma unroll
        for (int g = 0; g < 8; ++g) {
            const int gg = g ^ q;             // spread LDS banks across q
            f16x8 o;
#pragma unroll
            for (int e = 0; e < 8; ++e) o[e] = (_Float16)(tile[pp][q * 64 + gg * 8 + e] * inv);
            *reinterpret_cast<f16x8*>(dst + gg * 8) = o;
        }
    }
}

// ---------------- k_main staging (half-tile: 4 loads/thread) ----------------
// LDS tile: 64 j-rows x 512B (32 chunks of 16B). Slot chunk c of row j holds
// global chunk c ^ swz(j), swz(j) = (j&7) ^ (((j>>3)&3)<<1). Linear LDS dest +
// pre-swizzled global source (rule #21).
__device__ __forceinline__ void stage_half(const _Float16* __restrict__ feats, int jbase,
                                           _Float16* bufp, int tid, int half) {
#pragma unroll
    for (int s4 = 0; s4 < 4; ++s4) {
        const int sweep = half * 4 + s4;
        const int ch = sweep * 256 + tid;     // 0..2047 = 64 rows * 32 chunks
        const int j  = ch >> 5;
        const int c  = ch & 31;
        const int swz = (j & 7) ^ (((j >> 3) & 3) << 1);
        const _Float16* src = feats + ((size_t)(jbase + j)) * CDIM + (c ^ swz) * 8;
        __builtin_amdgcn_global_load_lds(
            (const __attribute__((address_space(1))) void*)src,
            (__attribute__((address_space(3))) void*)(bufp + (size_t)ch * 8),
            16, 0, 0);
    }
}

// ---------------- k_main: fused sim/exp/masked-rowsum (fp16, sorted) ---------
// 4 waves x 64 i-rows, 2 blocks/CU. B-frags resident (128 VGPR); FOUR MFMA
// accumulator chains (c00..c11, 64 regs) so per-wave issue runs are 128cy.
// k-loop split into 4 phases: {8 ds_read -> lgkmcnt(0) -> setprio(1) ->
// 16 MFMA -> setprio(0)}. Staging split 4+4 with counted vmcnt(4) (never 0).
__global__ __launch_bounds__(256, 2) void k_main(const _Float16* __restrict__ feats,
                                                 const int* __restrict__ labels,
                                                 const int* __restrict__ tcl,
                                                 float2* __restrict__ partials) {
    __shared__ __align__(16) _Float16 buf[2][64 * 256];   // 2 x 32KB
    const int tid  = threadIdx.x;
    const int w    = tid >> 6, lane = tid & 63;
    const int lo   = lane & 31, hi = lane >> 5;
    const int rb = blockIdx.x, slice = blockIdx.y;
    const int ibase = rb * 256 + w * 64;

    const int labi0 = labels[ibase + lo];
    const int labi1 = labels[ibase + 32 + lo];

    // B fragments (i-side), resident all kernel.
    // 32x32x16 B layout: lane holds col = lane&31, k = (lane>>5)*8 + e.
    f16x8 b0[16], b1[16];
    {
        const f16x8* r0 = (const f16x8*)(feats + (size_t)(ibase + lo) * CDIM + hi * 8);
        const f16x8* r1 = (const f16x8*)(feats + (size_t)(ibase + 32 + lo) * CDIM + hi * 8);
#pragma unroll
        for (int ks = 0; ks < 16; ++ks) { b0[ks] = r0[ks * 2]; b1[ks] = r1[ks * 2]; }
    }

    // swizzled read addressing: chunk (2ks+hi)^swz(lo); halves offset =
    // lo*256 + ((hi^s0)<<3) + (((ks&3)^sp)<<4) + ((ks&12)<<4)  [+8192 for jg1]
    const int s  = (lo & 7) ^ (((lo >> 3) & 3) << 1);
    const int sp = s >> 1;
    const int x0h = (s & 1) << 3;
    int idx4[4];
#pragma unroll
    for (int m = 0; m < 4; ++m)
        idx4[m] = lo * 256 + ((hi << 3) ^ x0h) + ((m ^ sp) << 4);

    float accA0 = 0.f, accP0 = 0.f, accA1 = 0.f, accP1 = 0.f;

    stage_half(feats, slice * 64, &buf[0][0], tid, 0);
    stage_half(feats, slice * 64, &buf[0][0], tid, 1);

#pragma unroll 1
    for (int ti = 0; ti < TPS; ++ti) {
        const int jt = slice + ti * NSL;
        const bool nxt = (ti + 1 < TPS);
        // uniform-index SMEM load (lgkm-counted; must not pollute vmcnt math)
        const int tc = tcl[__builtin_amdgcn_readfirstlane(jt)];

        if (nxt) {
            stage_half(feats, (jt + NSL) * 64, &buf[(ti + 1) & 1][0], tid, 0);
            asm volatile("s_waitcnt vmcnt(4)" ::: "memory");  // tile ti fully landed
        } else {
            asm volatile("s_waitcnt vmcnt(0)" ::: "memory");
        }
        __builtin_amdgcn_s_barrier();              // tile ti visible to all waves
        __builtin_amdgcn_sched_barrier(0);

        const _Float16* bc = &buf[ti & 1][0];
        f32x16 c00 = {0,0,0,0,0,0,0,0,0,0,0,0,0,0,0,0};
        f32x16 c01 = c00, c10 = c00, c11 = c00;

#pragma unroll
        for (int ph = 0; ph < 4; ++ph) {
            f16x8 a0[4], a1[4];
#pragma unroll
            for (int m = 0; m < 4; ++m) {
                const int off = idx4[m] + (ph << 6);          // (ks&12)<<4 = ph*64
                a0[m] = *reinterpret_cast<const f16x8*>(bc + off);
                a1[m] = *reinterpret_cast<const f16x8*>(bc + 8192 + off);
            }
            if (ph == 0 && nxt)
                stage_half(feats, (jt + NSL) * 64, &buf[(ti + 1) & 1][0], tid, 1);
            asm volatile("s_waitcnt lgkmcnt(0)" ::: "memory");
            __builtin_amdgcn_sched_barrier(0);
            __builtin_amdgcn_s_setprio(1);
#pragma unroll
            for (int m = 0; m < 4; ++m) {
                const int ks = ph * 4 + m;
                c00 = __builtin_amdgcn_mfma_f32_32x32x16_f16(a0[m], b0[ks], c00, 0, 0, 0);
                c01 = __builtin_amdgcn_mfma_f32_32x32x16_f16(a0[m], b1[ks], c01, 0, 0, 0);
                c10 = __builtin_amdgcn_mfma_f32_32x32x16_f16(a1[m], b0[ks], c10, 0, 0, 0);
                c11 = __builtin_amdgcn_mfma_f32_32x32x16_f16(a1[m], b1[ks], c11, 0, 0, 0);
            }
            __builtin_amdgcn_s_setprio(0);
        }

        // epilogue. C/D layout: col(i)=lane&31, row(j)=(reg&3)+8*(reg>>2)+4*hi
        if (tc != -2) {
            float t0 = 0.f, t1 = 0.f, t2 = 0.f, t3 = 0.f;
#pragma unroll
            for (int v = 0; v < 16; ++v) {
                t0 += exp2_fast(c00[v]);
                t1 += exp2_fast(c01[v]);
                t2 += exp2_fast(c10[v]);
                t3 += exp2_fast(c11[v]);
            }
            accA0 += t0 + t2; accA1 += t1 + t3;
            accP0 += (tc == labi0) ? (t0 + t2) : 0.f;
            accP1 += (tc == labi1) ? (t1 + t3) : 0.f;
        } else {
            const int jb = jt * 64;
#pragma unroll
            for (int q = 0; q < 4; ++q) {
                const int4 lj0 = *reinterpret_cast<const int4*>(labels + jb + q * 8 + hi * 4);
                const int4 lj1 = *reinterpret_cast<const int4*>(labels + jb + 32 + q * 8 + hi * 4);
#pragma unroll
                for (int r = 0; r < 4; ++r) {
                    const int l0 = (r == 0) ? lj0.x : (r == 1) ? lj0.y : (r == 2) ? lj0.z : lj0.w;
                    const int l1 = (r == 0) ? lj1.x : (r == 1) ? lj1.y : (r == 2) ? lj1.z : lj1.w;
                    const int v = q * 4 + r;
                    float e;
                    e = exp2_fast(c00[v]); accA0 += e; accP0 += (l0 == labi0) ? e : 0.f;
                    e = exp2_fast(c01[v]); accA1 += e; accP1 += (l0 == labi1) ? e : 0.f;
                    e = exp2_fast(c10[v]); accA0 += e; accP0 += (l1 == labi0) ? e : 0.f;
                    e = exp2_fast(c11[v]); accA1 += e; accP1 += (l1 == labi1) ? e : 0.f;
                }
            }
        }
        __builtin_amdgcn_s_barrier();   // all waves done reading buf[ti&1]
    }

    // diagonal term: ||b_i||^2 (feats pre-scaled, so this IS sim_ii*SCALE)
    float n0 = 0.f, n1 = 0.f;
#pragma unroll
    for (int ks = 0; ks < 16; ++ks)
#pragma unroll
        for (int e = 0; e < 8; ++e) {
            float v0 = (float)b0[ks][e]; n0 += v0 * v0;
            float v1 = (float)b1[ks][e]; n1 += v1 * v1;
        }
    n0 += __shfl_xor(n0, 32); n1 += __shfl_xor(n1, 32);

    // merge the two k-halves (lanes l and l^32 hold the same i)
    accA0 += __shfl_xor(accA0, 32); accP0 += __shfl_xor(accP0, 32);
    accA1 += __shfl_xor(accA1, 32); accP1 += __shfl_xor(accP1, 32);

    // subtract diagonal exactly once (owner slice of the tile containing j==i)
    if (((rb * 4 + w) & (NSL - 1)) == slice) {
        float e0 = exp2_fast(n0), e1 = exp2_fast(n1);
        accA0 -= e0; accP0 -= e0;
        accA1 -= e1; accP1 -= e1;
    }

    if (hi == 0) {
        size_t base = ((size_t)(rb * NSL + slice)) * 256 + w * 64;
        partials[base + lo]      = make_float2(accA0, accP0);
        partials[base + 32 + lo] = make_float2(accA1, accP1);
    }
}

// ---------------- k_reduce: per-row loss + global accumulate + finalize ------
__global__ void k_reduce(const float2* __restrict__ partials, float* __restrict__ accum,
                         int* __restrict__ done, float* __restrict__ out) {
    const int rb = blockIdx.x;          // 60
    const int rl = threadIdx.x;         // 256
    const int t  = rb * 256 + rl;
    float sA = -NPADJ, sP = 0.f;        // pad columns contribute exp2(0)=1 each
#pragma unroll
    for (int s = 0; s < NSL; ++s) {
        float2 v = partials[((size_t)(rb * NSL + s)) * 256 + rl];
        sA += v.x; sP += v.y;
    }
    float per = 0.f, cnt = 0.f;
    if (t < T_REAL && sP > 0.f) {
        per = logf(sA) - logf(sP);      // = -(log(pos) - log(all))
        cnt = 1.f;
    }
#pragma unroll
    for (int off = 32; off >= 1; off >>= 1) {
        per += __shfl_xor(per, off);
        cnt += __shfl_xor(cnt, off);
    }
    if ((rl & 63) == 0) { atomicAdd(&accum[0], per); atomicAdd(&accum[1], cnt); }
    __syncthreads();
    if (rl == 0) {
        __threadfence();
        if (atomicAdd(done, 1) == NRB - 1) {
            float a = atomicAdd(&accum[0], 0.f);   // device-scope coherent read
            float c = atomicAdd(&accum[1], 0.f);
            out[0] = a / fmaxf(c, 1.f);
        }
    }
}

// ---------------- launch ----------------
extern "C" void kernel_launch(void* const* d_in, const int* in_sizes, int n_in,
                              void* d_out, int out_size, void* d_ws, size_t ws_size,
                              hipStream_t stream) {
    const float* emb     = (const float*)d_in[0];
    const int*   targets = (const int*)d_in[1];
    float*       out     = (float*)d_out;
    char*        ws      = (char*)d_ws;

    _Float16* feats    = (_Float16*)(ws + OFF_FEATS);
    int*      labels   = (int*)(ws + OFF_LAB);
    int*      rank     = (int*)(ws + OFF_RANK);
    int*      tcl      = (int*)(ws + OFF_TCL);
    int*      done     = (int*)(ws + OFF_DONE);
    float2*   partials = (float2*)(ws + OFF_PART);
    float*    accum    = (float*)(ws + OFF_ACC);

    k_sort  <<<dim3(1),        dim3(1024), 0, stream>>>(targets, rank, labels, tcl, accum, done);
    k_prep  <<<dim3(60, 4),    dim3(256),  0, stream>>>(emb, rank, feats);
    k_main  <<<dim3(NRB, NSL), dim3(256),  0, stream>>>(feats, labels, tcl, partials);
    k_reduce<<<dim3(NRB),      dim3(256),  0, stream>>>(partials, accum, done, out);
}

// Round 8
// 252.232 us; speedup vs baseline: 1.0365x; 1.0365x over previous
//
#include <hip/hip_runtime.h>
#include <cstdint>
#include <cstddef>

// ---------------- problem constants ----------------
#define T_REAL 14884        // 4*61*61 real pixels
#define TPAD   15360        // padded to 60*256
#define CDIM   256
#define HW     3721         // 61*61
#define NRB    60           // row blocks of 256 (8 waves x 32 rows)
#define NSL    16           // column slices (grid.y)
#define TPS    15           // 64-wide j-tiles per slice (240/16)
#define NT     240          // total j-tiles
#define NPADJ  476.0f       // TPAD - T_REAL

// feats pre-scaled by sqrt(log2(e)/0.07): MFMA output IS sim*log2(e)/temp.
static constexpr float SQRT_SCALE = 4.53981598f;   // sqrt(20.6099291555566)

typedef _Float16 f16x8  __attribute__((ext_vector_type(8)));
typedef float    f32x16 __attribute__((ext_vector_type(16)));

__device__ __forceinline__ float exp2_fast(float x) {
#if __has_builtin(__builtin_amdgcn_exp2f)
    return __builtin_amdgcn_exp2f(x);
#else
    return exp2f(x);
#endif
}

// ---------------- workspace layout (bytes) ----------------
#define OFF_FEATS 0u
#define SZ_FEATS  ((unsigned)TPAD * CDIM * 2u)            // 7,864,320
#define OFF_LAB   (OFF_FEATS + SZ_FEATS)                  // TPAD ints
#define OFF_RANK  (OFF_LAB + (unsigned)TPAD * 4u)         // T_REAL ints (rounded)
#define OFF_TCL   (OFF_RANK + 59648u)                     // NT ints -> 1024
#define OFF_DONE  (OFF_TCL + 1024u)                       // 1 int (+pad to 128)
#define OFF_PART  (OFF_DONE + 128u)                       // NRB*NSL*256 float2
#define SZ_PART   ((unsigned)NRB * NSL * 256u * 8u)       // 1,966,080
#define OFF_ACC   (OFF_PART + SZ_PART)                    // 2 floats

// ---------------- k_sort: hist + scan + rank + labels + tcl + zeros ----------
__global__ void k_sort(const int* __restrict__ targets, int* __restrict__ rank,
                       int* __restrict__ labels, int* __restrict__ tcl,
                       float* __restrict__ accum, int* __restrict__ done) {
    __shared__ int h[5], cur[5], soffs[6];
    const int tid = threadIdx.x, lane = tid & 63;
    if (tid < 5) h[tid] = 0;
    if (tid == 8) { accum[0] = 0.f; accum[1] = 0.f; }
    if (tid == 9) done[0] = 0;
    __syncthreads();

    for (int t = tid; t < T_REAL; t += 1024) {
        const int c = targets[t];
#pragma unroll
        for (int cl = 0; cl < 5; ++cl) {
            unsigned long long m = __ballot(c == cl);
            if (c == cl && lane == __ffsll(m) - 1) atomicAdd(&h[cl], (int)__popcll(m));
        }
    }
    __syncthreads();
    if (tid == 0) {
        int o = 0;
#pragma unroll
        for (int c = 0; c < 5; ++c) { soffs[c] = o; cur[c] = o; o += h[c]; }
        soffs[5] = o;                  // == T_REAL
    }
    __syncthreads();

    for (int t = tid; t < T_REAL; t += 1024) {
        const int c = targets[t];
#pragma unroll
        for (int cl = 0; cl < 5; ++cl) {
            unsigned long long m = __ballot(c == cl);
            if (c == cl) {
                const int leader = __ffsll(m) - 1;
                int base = 0;
                if (lane == leader) base = atomicAdd(&cur[cl], (int)__popcll(m));
                base = __shfl(base, leader);
                const int r = base + (int)__popcll(m & ((1ull << lane) - 1ull));
                rank[t] = r;
                labels[r] = c;
            }
        }
    }
    for (int t = T_REAL + tid; t < TPAD; t += 1024) labels[t] = -1;

    for (int t = tid; t < NT; t += 1024) {
        const int lo = t * 64, hi = lo + 64;
        int tc = -2;
        if (lo >= T_REAL) tc = -1;
        else {
#pragma unroll
            for (int c = 0; c < 5; ++c)
                if (lo >= soffs[c] && hi <= soffs[c + 1]) tc = c;
        }
        tcl[t] = tc;
    }
}

// ---------------- k_prep: norm+transpose+scale+cast, scattered to sorted rows
__global__ void k_prep(const float* __restrict__ emb, const int* __restrict__ rank,
                       _Float16* __restrict__ feats) {
    const int tid = threadIdx.x;
    const int bx = blockIdx.x, n = blockIdx.y;

    if (bx == 59) {            // tail block: zero this n's share of pad rows
        const int r0 = T_REAL + n * 119;
        f16x8 z = {0, 0, 0, 0, 0, 0, 0, 0};
        for (int c = tid; c < 119 * 32; c += 256) {
            int rr = r0 + (c >> 5), cc = c & 31;
            *reinterpret_cast<f16x8*>(feats + (size_t)rr * CDIM + cc * 8) = z;
        }
        return;
    }

    __shared__ float tile[64][257];
    __shared__ float sspart[4][64];
    const int lane = tid & 63, w = tid >> 6;
    const int px0 = bx * 64;
    const int hw = px0 + lane;

    float ssq = 0.f;
    for (int ci = w; ci < CDIM; ci += 4) {
        float v = (hw < HW) ? emb[((size_t)(n * CDIM + ci)) * HW + hw] : 0.f;
        tile[lane][ci] = v;
        ssq += v * v;
    }
    sspart[w][lane] = ssq;
    __syncthreads();

    const int pp = tid >> 2, q = tid & 3;     // pixel-in-tile, channel quarter
    float s2 = sspart[q][pp];
    s2 += __shfl_xor(s2, 1);
    s2 += __shfl_xor(s2, 2);
    const float inv = SQRT_SCALE / fmaxf(sqrtf(s2), 1e-12f);

    const int hwp = px0 + pp;
    if (hwp < HW) {
        const int row = rank[n * HW + hwp];
        _Float16* dst = feats + (size_t)row * CDIM + q * 64;
#pragma unroll
        for (int g = 0; g < 8; ++g) {
            const int gg = g ^ q;             // spread LDS banks across q
            f16x8 o;
#pragma unroll
            for (int e = 0; e < 8; ++e) o[e] = (_Float16)(tile[pp][q * 64 + gg * 8 + e] * inv);
            *reinterpret_cast<f16x8*>(dst + gg * 8) = o;
        }
    }
}

// ---------------- k_main staging: 4 loads/thread at 512 threads --------------
// LDS tile: 64 j-rows x 512B (32 chunks of 16B). Slot chunk c of row j holds
// global chunk c ^ swz(j), swz(j) = (j&7) ^ (((j>>3)&3)<<1). Linear LDS dest +
// pre-swizzled global source (rule #21).
__device__ __forceinline__ void stage_tile(const _Float16* __restrict__ feats, int jbase,
                                           _Float16* bufp, int tid) {
#pragma unroll
    for (int sweep = 0; sweep < 4; ++sweep) {
        const int ch = sweep * 512 + tid;     // 0..2047 = 64 rows * 32 chunks
        const int j  = ch >> 5;
        const int c  = ch & 31;
        const int swz = (j & 7) ^ (((j >> 3) & 3) << 1);
        const _Float16* src = feats + ((size_t)(jbase + j)) * CDIM + (c ^ swz) * 8;
        __builtin_amdgcn_global_load_lds(
            (const __attribute__((address_space(1))) void*)src,
            (__attribute__((address_space(3))) void*)(bufp + (size_t)ch * 8),
            16, 0, 0);
    }
}

// ---------------- k_main: fused sim/exp/masked-rowsum (fp16, sorted) ---------
// 8 waves x 32 i-rows = 256 rows/block, 2 blocks/CU -> 4 waves/SIMD.
// Per wave: B = 16 f16x8 (64 VGPR), 2 acc chains (cA=j[0:32), cB=j[32:64)).
// ~127 regs total -> fits the 128-reg occupancy step. Compiler-scheduled
// MFMA loop (m97: lgkm scheduling near-optimal); counted vmcnt(4) staging.
__global__ __launch_bounds__(512, 2) void k_main(const _Float16* __restrict__ feats,
                                                 const int* __restrict__ labels,
                                                 const int* __restrict__ tcl,
                                                 float2* __restrict__ partials) {
    __shared__ __align__(16) _Float16 buf[2][64 * 256];   // 2 x 32KB
    const int tid  = threadIdx.x;
    const int w    = tid >> 6, lane = tid & 63;
    const int lo   = lane & 31, hi = lane >> 5;
    const int rb = blockIdx.x, slice = blockIdx.y;
    const int ibase = rb * 256 + w * 32;

    const int labi = labels[ibase + lo];

    // B fragments (i-side), resident all kernel.
    // 32x32x16 B layout: lane holds col = lane&31, k = (lane>>5)*8 + e.
    f16x8 b[16];
    {
        const f16x8* r0 = (const f16x8*)(feats + (size_t)(ibase + lo) * CDIM + hi * 8);
#pragma unroll
        for (int ks = 0; ks < 16; ++ks) b[ks] = r0[ks * 2];
    }

    // swizzled read addressing: chunk (2ks+hi)^swz(lo); halves offset =
    // lo*256 + ((hi^s0)<<3) + (((ks&3)^sp)<<4) + ((ks&12)<<4)  [+8192 for jg1]
    const int s  = (lo & 7) ^ (((lo >> 3) & 3) << 1);
    const int sp = s >> 1;
    const int x0h = (s & 1) << 3;
    int idx4[4];
#pragma unroll
    for (int m = 0; m < 4; ++m)
        idx4[m] = lo * 256 + ((hi << 3) ^ x0h) + ((m ^ sp) << 4);

    float accA = 0.f, accP = 0.f;

    stage_tile(feats, slice * 64, &buf[0][0], tid);

#pragma unroll 1
    for (int ti = 0; ti < TPS; ++ti) {
        const int jt = slice + ti * NSL;
        // uniform-index SMEM load (lgkm-counted; doesn't pollute vmcnt math)
        const int tc = tcl[__builtin_amdgcn_readfirstlane(jt)];

        if (ti + 1 < TPS) {
            stage_tile(feats, (jt + NSL) * 64, &buf[(ti + 1) & 1][0], tid);
            asm volatile("s_waitcnt vmcnt(4)" ::: "memory");  // tile ti fully landed
        } else {
            asm volatile("s_waitcnt vmcnt(0)" ::: "memory");
        }
        __builtin_amdgcn_s_barrier();              // tile ti visible to all waves
        __builtin_amdgcn_sched_barrier(0);

        const _Float16* bc = &buf[ti & 1][0];
        f32x16 cA = {0,0,0,0,0,0,0,0,0,0,0,0,0,0,0,0};
        f32x16 cB = cA;

#pragma unroll
        for (int ks = 0; ks < 16; ++ks) {
            const int off = idx4[ks & 3] + ((ks & 12) << 4);
            const f16x8 a_lo = *reinterpret_cast<const f16x8*>(bc + off);
            const f16x8 a_hi = *reinterpret_cast<const f16x8*>(bc + 8192 + off);
            cA = __builtin_amdgcn_mfma_f32_32x32x16_f16(a_lo, b[ks], cA, 0, 0, 0);
            cB = __builtin_amdgcn_mfma_f32_32x32x16_f16(a_hi, b[ks], cB, 0, 0, 0);
        }

        // epilogue. C/D layout: col(i)=lane&31, row(j)=(reg&3)+8*(reg>>2)+4*hi
        if (tc != -2) {
            float t0 = 0.f, t1 = 0.f;
#pragma unroll
            for (int v = 0; v < 16; ++v) {
                t0 += exp2_fast(cA[v]);
                t1 += exp2_fast(cB[v]);
            }
            accA += t0 + t1;
            accP += (tc == labi) ? (t0 + t1) : 0.f;
        } else {
            const int jb = jt * 64;
#pragma unroll
            for (int q = 0; q < 4; ++q) {
                const int4 lj0 = *reinterpret_cast<const int4*>(labels + jb + q * 8 + hi * 4);
                const int4 lj1 = *reinterpret_cast<const int4*>(labels + jb + 32 + q * 8 + hi * 4);
#pragma unroll
                for (int r = 0; r < 4; ++r) {
                    const int l0 = (r == 0) ? lj0.x : (r == 1) ? lj0.y : (r == 2) ? lj0.z : lj0.w;
                    const int l1 = (r == 0) ? lj1.x : (r == 1) ? lj1.y : (r == 2) ? lj1.z : lj1.w;
                    const int v = q * 4 + r;
                    float e;
                    e = exp2_fast(cA[v]); accA += e; accP += (l0 == labi) ? e : 0.f;
                    e = exp2_fast(cB[v]); accA += e; accP += (l1 == labi) ? e : 0.f;
                }
            }
        }
        __builtin_amdgcn_s_barrier();   // all waves done reading buf[ti&1]
    }

    // diagonal term: ||b_i||^2 (feats pre-scaled, so this IS sim_ii*SCALE)
    float nsq = 0.f;
#pragma unroll
    for (int ks = 0; ks < 16; ++ks)
#pragma unroll
        for (int e = 0; e < 8; ++e) { float v0 = (float)b[ks][e]; nsq += v0 * v0; }
    nsq += __shfl_xor(nsq, 32);

    // merge the two k-halves (lanes l and l^32 hold the same i)
    accA += __shfl_xor(accA, 32);
    accP += __shfl_xor(accP, 32);

    // subtract diagonal exactly once (owner slice of the tile containing j==i)
    if (((rb * 4 + (w >> 1)) & (NSL - 1)) == slice) {
        float e0 = exp2_fast(nsq);
        accA -= e0; accP -= e0;
    }

    if (hi == 0) {
        partials[((size_t)(rb * NSL + slice)) * 256 + w * 32 + lo] = make_float2(accA, accP);
    }
}

// ---------------- k_reduce: per-row loss + global accumulate + finalize ------
__global__ void k_reduce(const float2* __restrict__ partials, float* __restrict__ accum,
                         int* __restrict__ done, float* __restrict__ out) {
    const int rb = blockIdx.x;          // 60
    const int rl = threadIdx.x;         // 256
    const int t  = rb * 256 + rl;
    float sA = -NPADJ, sP = 0.f;        // pad columns contribute exp2(0)=1 each
#pragma unroll
    for (int s = 0; s < NSL; ++s) {
        float2 v = partials[((size_t)(rb * NSL + s)) * 256 + rl];
        sA += v.x; sP += v.y;
    }
    float per = 0.f, cnt = 0.f;
    if (t < T_REAL && sP > 0.f) {
        per = logf(sA) - logf(sP);      // = -(log(pos) - log(all))
        cnt = 1.f;
    }
#pragma unroll
    for (int off = 32; off >= 1; off >>= 1) {
        per += __shfl_xor(per, off);
        cnt += __shfl_xor(cnt, off);
    }
    if ((rl & 63) == 0) { atomicAdd(&accum[0], per); atomicAdd(&accum[1], cnt); }
    __syncthreads();
    if (rl == 0) {
        __threadfence();
        if (atomicAdd(done, 1) == NRB - 1) {
            float a = atomicAdd(&accum[0], 0.f);   // device-scope coherent read
            float c = atomicAdd(&accum[1], 0.f);
            out[0] = a / fmaxf(c, 1.f);
        }
    }
}

// ---------------- launch ----------------
extern "C" void kernel_launch(void* const* d_in, const int* in_sizes, int n_in,
                              void* d_out, int out_size, void* d_ws, size_t ws_size,
                              hipStream_t stream) {
    const float* emb     = (const float*)d_in[0];
    const int*   targets = (const int*)d_in[1];
    float*       out     = (float*)d_out;
    char*        ws      = (char*)d_ws;

    _Float16* feats    = (_Float16*)(ws + OFF_FEATS);
    int*      labels   = (int*)(ws + OFF_LAB);
    int*      rank     = (int*)(ws + OFF_RANK);
    int*      tcl      = (int*)(ws + OFF_TCL);
    int*      done     = (int*)(ws + OFF_DONE);
    float2*   partials = (float2*)(ws + OFF_PART);
    float*    accum    = (float*)(ws + OFF_ACC);

    k_sort  <<<dim3(1),        dim3(1024), 0, stream>>>(targets, rank, labels, tcl, accum, done);
    k_prep  <<<dim3(60, 4),    dim3(256),  0, stream>>>(emb, rank, feats);
    k_main  <<<dim3(NRB, NSL), dim3(512),  0, stream>>>(feats, labels, tcl, partials);
    k_reduce<<<dim3(NRB),      dim3(256),  0, stream>>>(partials, accum, done, out);
}